// Round 3
// baseline (78.731 us; speedup 1.0000x reference)
//
#include <hip/hip_runtime.h>

#define NA 96
#define NB 96
#define NS 64
#define TABLE_FLOATS (NA * NB * NS)   // 589824 floats = 2.25 MiB

// ---------------------------------------------------------------------------
// Warming kernel: pull the whole rel table into EVERY XCD's L2.
// Grid = 2048 blocks; HW dispatches blocks round-robin over the 8 XCDs
// (blockIdx%8 ~ XCD), so blocks {8s+x : s=0..255} on XCD x together stream
// slices 0..255 = the full table into that XCD's L2 (2.25 MiB < 4 MiB).
// Coalesced float4 reads; sum written to d_ws to defeat DCE.
// ---------------------------------------------------------------------------
__global__ __launch_bounds__(256) void warm_l2_kernel(
    const float4* __restrict__ rel4,   // table as float4[147456]
    float* __restrict__ sink)          // d_ws
{
    const int slice = blockIdx.x >> 3;            // 0..255
    const int base  = slice * (TABLE_FLOATS / 256 / 4);  // 576 float4 per slice
    float s = 0.0f;
    #pragma unroll
    for (int i = 0; i < 3; ++i) {
        int pos = threadIdx.x + (i << 8);
        if (pos < 576) {
            float4 v = rel4[base + pos];
            s += v.x + v.y + v.z + v.w;
        }
    }
    // one write per block, keeps the loads live; d_ws is scratch
    if (threadIdx.x == 0) sink[blockIdx.x] = s;
}

// ---------------------------------------------------------------------------
// Main kernel (unchanged from round 2, verified absmax 0.0).
// ---------------------------------------------------------------------------
template <int K>
__device__ __forceinline__ void soft_accum_tpl(
    int tid, int vx, int vy, int vz,
    float qx, float qy, float qz, float inv_t,
    const float* __restrict__ rel,
    float& sw, float& swm)
{
    constexpr int K2 = K * K;
    constexpr int K3 = K * K * K;
    constexpr int R  = K / 2;
    constexpr int ITER = (K3 + 255) / 256;

    #pragma unroll
    for (int i = 0; i < ITER; ++i) {
        int k = tid + i * 256;
        bool valid = (k < K3);
        int kk = valid ? k : 0;
        int ox  = kk / K2;
        int rem = kk - ox * K2;
        int oy  = rem / K;
        int oz  = rem - oy * K;

        int cx = vx + ox - R; cx = min(max(cx, 0), NA - 1);
        int cy = vy + oy - R; cy = min(max(cy, 0), NB - 1);
        int cz = vz + oz - R; cz = min(max(cz, 0), NS - 1);

        float dx = qx - (float)cx;
        float dy = qy - (float)cy;
        float dz = qz - (float)cz;
        float d  = dx * dx + dy * dy + dz * dz;

        float m = rel[(cx * NB + cy) * NS + cz];
        float w = valid ? __expf(-d * inv_t) : 0.0f;
        sw  += w;
        swm += w * m;
    }
}

__device__ __noinline__ void soft_accum_generic(
    int tid, int vx, int vy, int vz, int K,
    float qx, float qy, float qz, float inv_t,
    const float* __restrict__ rel,
    float& sw, float& swm)
{
    const int K2 = K * K;
    const int K3 = K2 * K;
    const int R  = K / 2;
    for (int k = tid; k < K3; k += 256) {
        int ox  = k / K2;
        int rem = k - ox * K2;
        int oy  = rem / K;
        int oz  = rem - oy * K;
        int cx = vx + ox - R; cx = min(max(cx, 0), NA - 1);
        int cy = vy + oy - R; cy = min(max(cy, 0), NB - 1);
        int cz = vz + oz - R; cz = min(max(cz, 0), NS - 1);
        float dx = qx - (float)cx;
        float dy = qy - (float)cy;
        float dz = qz - (float)cz;
        float d  = dx * dx + dy * dy + dz * dz;
        float w = __expf(-d * inv_t);
        sw  += w;
        swm += w * rel[(cx * NB + cy) * NS + cz];
    }
}

__global__ __launch_bounds__(256) void latent_lookup_kernel(
    const float* __restrict__ q,        // [B,3]
    const float* __restrict__ rel,      // [NA*NB*NS]
    const float* __restrict__ origin,   // [3]
    const float* __restrict__ spacing,  // [3]
    const float* __restrict__ temp,     // [1]
    const int*   __restrict__ ksize,    // [1]
    float* __restrict__ out,            // [2,B]
    int B)
{
    const int b   = blockIdx.x;
    const int tid = threadIdx.x;

    const float qx = q[b * 3 + 0];
    const float qy = q[b * 3 + 1];
    const float qz = q[b * 3 + 2];

    const float inv_t = 1.0f / (temp[0] + 1e-8f);
    const int   ks    = ksize[0];

    const float rx = (qx - origin[0]) / spacing[0];
    const float ry = (qy - origin[1]) / spacing[1];
    const float rz = (qz - origin[2]) / spacing[2];
    int vx = (int)rintf(rx); vx = min(max(vx, 1), NA - 2);
    int vy = (int)rintf(ry); vy = min(max(vy, 1), NB - 2);
    int vz = (int)rintf(rz); vz = min(max(vz, 1), NS - 2);

    float sw  = 0.0f;
    float swm = 0.0f;

    if (ks == 15) {
        soft_accum_tpl<15>(tid, vx, vy, vz, qx, qy, qz, inv_t, rel, sw, swm);
    } else {
        soft_accum_generic(tid, vx, vy, vz, ks, qx, qy, qz, inv_t, rel, sw, swm);
    }

    __shared__ float red[4][2];
    const int wave = tid >> 6;
    const int lane = tid & 63;
    #pragma unroll
    for (int off = 32; off > 0; off >>= 1) {
        sw  += __shfl_down(sw,  off);
        swm += __shfl_down(swm, off);
    }
    if (lane == 0) {
        red[wave][0] = sw;
        red[wave][1] = swm;
    }
    __syncthreads();

    if (tid == 0) {
        float tsw = 0.0f, tswm = 0.0f;
        #pragma unroll
        for (int w = 0; w < 4; ++w) {
            tsw  += red[w][0];
            tswm += red[w][1];
        }

        float fx = floorf(qx); int hx = (int)fx + ((qx - fx) > 0.5f ? 1 : 0);
        float fy = floorf(qy); int hy = (int)fy + ((qy - fy) > 0.5f ? 1 : 0);
        float fz = floorf(qz); int hz = (int)fz + ((qz - fz) > 0.5f ? 1 : 0);
        hx = min(max(hx, 0), NA - 1);
        hy = min(max(hy, 0), NB - 1);
        hz = min(max(hz, 0), NS - 1);

        out[b]     = rel[(hx * NB + hy) * NS + hz];   // hard
        out[B + b] = tswm / tsw;                      // soft
    }
}

extern "C" void kernel_launch(void* const* d_in, const int* in_sizes, int n_in,
                              void* d_out, int out_size, void* d_ws, size_t ws_size,
                              hipStream_t stream) {
    const float* q       = (const float*)d_in[0];  // [B,3]
    // d_in[1] = indices_3d — unit meshgrid, synthesized arithmetically
    const float* rel     = (const float*)d_in[2];  // [NA,NB,NS]
    const float* origin  = (const float*)d_in[3];  // [3]
    const float* spacing = (const float*)d_in[4];  // [3]
    const float* temp    = (const float*)d_in[5];  // [1]
    const int*   ksize   = (const int*)d_in[6];    // [1]
    float* out = (float*)d_out;

    const int B = in_sizes[0] / 3;

    // Phase 1: pull the table into every XCD's L2 (the 268 MB workspace poison
    // before each timed iteration evicts it from L2 AND L3).
    warm_l2_kernel<<<2048, 256, 0, stream>>>((const float4*)rel, (float*)d_ws);

    // Phase 2: the actual lookup — gathers now hit L2 instead of cold HBM.
    latent_lookup_kernel<<<B, 256, 0, stream>>>(q, rel, origin, spacing, temp,
                                                ksize, out, B);
}

// Round 5
// 76.036 us; speedup vs baseline: 1.0354x; 1.0354x over previous
//
#include <hip/hip_runtime.h>

#define NA 96
#define NB 96
#define NS 64
#define QUARTERS 4          // blocks per query
#define K3_15 3375
#define PER_Q 844           // ceil(3375/4)

// ---------------------------------------------------------------------------
// Soft-path partial accumulator over k in [k0, k1), compile-time K.
// All loads issued up-front (unrolled, predicated) for max MLP.
// ---------------------------------------------------------------------------
template <int K, int ITER>
__device__ __forceinline__ void soft_accum_range(
    int tid, int k0, int k1, int vx, int vy, int vz,
    float qx, float qy, float qz, float inv_t,
    const float* __restrict__ rel,
    float& sw, float& swm)
{
    constexpr int K2 = K * K;
    constexpr int R  = K / 2;

    #pragma unroll
    for (int i = 0; i < ITER; ++i) {
        int k = k0 + tid + i * 256;
        bool valid = (k < k1);
        int kk = valid ? k : 0;
        // constant divisors -> magic multiply
        int ox  = kk / K2;
        int rem = kk - ox * K2;
        int oy  = rem / K;
        int oz  = rem - oy * K;

        int cx = vx + ox - R; cx = min(max(cx, 0), NA - 1);
        int cy = vy + oy - R; cy = min(max(cy, 0), NB - 1);
        int cz = vz + oz - R; cz = min(max(cz, 0), NS - 1);

        float dx = qx - (float)cx;
        float dy = qy - (float)cy;
        float dz = qz - (float)cz;
        float d  = dx * dx + dy * dy + dz * dz;

        float m = rel[(cx * NB + cy) * NS + cz];
        float w = valid ? __expf(-d * inv_t) : 0.0f;
        sw  += w;
        swm += w * m;
    }
}

// ---------------------------------------------------------------------------
// Partial kernel: grid = B*4 blocks, block (b, qd) handles the qd-th quarter
// of query b's K^3 neighborhood. 2048 blocks -> 8 blocks/CU -> 32 waves/CU
// (occupancy max), 4x the in-flight scatter requests of the 512-block version.
// Deterministic partials to ws[b][qd][{sw,swm}]; no atomics.
// ---------------------------------------------------------------------------
__global__ __launch_bounds__(256) void latent_partial_kernel(
    const float* __restrict__ q,
    const float* __restrict__ rel,
    const float* __restrict__ origin,
    const float* __restrict__ spacing,
    const float* __restrict__ temp,
    const int*   __restrict__ ksize,
    float* __restrict__ ws,             // [B][4][2]
    int B)
{
    const int bx  = blockIdx.x;
    const int b   = bx >> 2;
    const int qd  = bx & 3;
    const int tid = threadIdx.x;

    const float qx = q[b * 3 + 0];
    const float qy = q[b * 3 + 1];
    const float qz = q[b * 3 + 2];

    const float inv_t = 1.0f / (temp[0] + 1e-8f);
    const int   ks    = ksize[0];

    const float rx = (qx - origin[0]) / spacing[0];
    const float ry = (qy - origin[1]) / spacing[1];
    const float rz = (qz - origin[2]) / spacing[2];
    int vx = (int)rintf(rx); vx = min(max(vx, 1), NA - 2);
    int vy = (int)rintf(ry); vy = min(max(vy, 1), NB - 2);
    int vz = (int)rintf(rz); vz = min(max(vz, 1), NS - 2);

    float sw  = 0.0f;
    float swm = 0.0f;

    if (ks == 15) {            // shipped configuration, uniform branch
        const int k0 = qd * PER_Q;
        const int k1 = min(K3_15, k0 + PER_Q);
        soft_accum_range<15, (PER_Q + 255) / 256>(
            tid, k0, k1, vx, vy, vz, qx, qy, qz, inv_t, rel, sw, swm);
    } else {                   // generic fallback (runtime K)
        const int K2 = ks * ks;
        const int K3 = K2 * ks;
        const int R  = ks / 2;
        const int per = (K3 + 3) >> 2;
        const int k0 = qd * per;
        const int k1 = min(K3, k0 + per);
        for (int k = k0 + tid; k < k1; k += 256) {
            int ox  = k / K2;
            int rem = k - ox * K2;
            int oy  = rem / ks;
            int oz  = rem - oy * ks;
            int cx = vx + ox - R; cx = min(max(cx, 0), NA - 1);
            int cy = vy + oy - R; cy = min(max(cy, 0), NB - 1);
            int cz = vz + oz - R; cz = min(max(cz, 0), NS - 1);
            float dx = qx - (float)cx;
            float dy = qy - (float)cy;
            float dz = qz - (float)cz;
            float d  = dx * dx + dy * dy + dz * dz;
            float w  = __expf(-d * inv_t);
            sw  += w;
            swm += w * rel[(cx * NB + cy) * NS + cz];
        }
    }

    // block reduction: wave shuffle then LDS across the 4 waves
    __shared__ float red[4][2];
    const int wave = tid >> 6;
    const int lane = tid & 63;
    #pragma unroll
    for (int off = 32; off > 0; off >>= 1) {
        sw  += __shfl_down(sw,  off);
        swm += __shfl_down(swm, off);
    }
    if (lane == 0) {
        red[wave][0] = sw;
        red[wave][1] = swm;
    }
    __syncthreads();

    if (tid == 0) {
        float tsw = 0.0f, tswm = 0.0f;
        #pragma unroll
        for (int w = 0; w < 4; ++w) {
            tsw  += red[w][0];
            tswm += red[w][1];
        }
        ws[(b * 4 + qd) * 2 + 0] = tsw;
        ws[(b * 4 + qd) * 2 + 1] = tswm;
    }
}

// ---------------------------------------------------------------------------
// Finalize: one thread per query. Sum the 4 partials (two aligned float4
// loads), divide, and do the hard-path nearest-lattice gather.
// ---------------------------------------------------------------------------
__global__ __launch_bounds__(256) void latent_finalize_kernel(
    const float* __restrict__ q,
    const float* __restrict__ rel,
    const float* __restrict__ ws,       // [B][4][2]
    float* __restrict__ out,            // [2,B]
    int B)
{
    const int idx = blockIdx.x * 256 + threadIdx.x;
    if (idx >= B) return;

    const float4* w4 = (const float4*)(ws + idx * 8);
    float4 a = w4[0];
    float4 c = w4[1];
    float sw  = a.x + a.z + c.x + c.z;
    float swm = a.y + a.w + c.y + c.w;

    const float qx = q[idx * 3 + 0];
    const float qy = q[idx * 3 + 1];
    const float qz = q[idx * 3 + 2];

    // hard: nearest lattice point; ties (frac==0.5) -> floor, matching
    // argmin first-minimum (lower flat index) semantics.
    float fx = floorf(qx); int hx = (int)fx + ((qx - fx) > 0.5f ? 1 : 0);
    float fy = floorf(qy); int hy = (int)fy + ((qy - fy) > 0.5f ? 1 : 0);
    float fz = floorf(qz); int hz = (int)fz + ((qz - fz) > 0.5f ? 1 : 0);
    hx = min(max(hx, 0), NA - 1);
    hy = min(max(hy, 0), NB - 1);
    hz = min(max(hz, 0), NS - 1);

    out[idx]     = rel[(hx * NB + hy) * NS + hz];
    out[B + idx] = swm / sw;
}

extern "C" void kernel_launch(void* const* d_in, const int* in_sizes, int n_in,
                              void* d_out, int out_size, void* d_ws, size_t ws_size,
                              hipStream_t stream) {
    const float* q       = (const float*)d_in[0];  // [B,3]
    // d_in[1] = indices_3d — unit meshgrid, synthesized arithmetically
    const float* rel     = (const float*)d_in[2];  // [NA,NB,NS]
    const float* origin  = (const float*)d_in[3];  // [3]
    const float* spacing = (const float*)d_in[4];  // [3]
    const float* temp    = (const float*)d_in[5];  // [1]
    const int*   ksize   = (const int*)d_in[6];    // [1]
    float* out = (float*)d_out;
    float* ws  = (float*)d_ws;

    const int B = in_sizes[0] / 3;

    latent_partial_kernel<<<B * QUARTERS, 256, 0, stream>>>(
        q, rel, origin, spacing, temp, ksize, ws, B);

    latent_finalize_kernel<<<(B + 255) / 256, 256, 0, stream>>>(
        q, rel, ws, out, B);
}

// Round 6
// 74.376 us; speedup vs baseline: 1.0586x; 1.0223x over previous
//
#include <hip/hip_runtime.h>

#define NA 96
#define NB 96
#define NS 64

// ---------------------------------------------------------------------------
// Single-launch kernel (one launch = minimum graph-replay overhead; measured
// best across R1-R5). Soft path: 3375 neighbors unrolled 14-deep per thread
// for max memory-level parallelism. Hard path: nearest-lattice gather issued
// AT THE TOP so its ~900cy cold-HBM latency overlaps the soft gathers instead
// of serializing on the block tail after the reduction.
// ---------------------------------------------------------------------------
template <int K>
__device__ __forceinline__ void soft_accum_tpl(
    int tid, int vx, int vy, int vz,
    float qx, float qy, float qz, float inv_t,
    const float* __restrict__ rel,
    float& sw, float& swm)
{
    constexpr int K2 = K * K;
    constexpr int K3 = K * K * K;
    constexpr int R  = K / 2;
    constexpr int ITER = (K3 + 255) / 256;

    #pragma unroll
    for (int i = 0; i < ITER; ++i) {
        int k = tid + i * 256;
        bool valid = (k < K3);
        int kk = valid ? k : 0;
        // constant divisors -> magic multiply, no div emulation
        int ox  = kk / K2;
        int rem = kk - ox * K2;
        int oy  = rem / K;
        int oz  = rem - oy * K;

        int cx = vx + ox - R; cx = min(max(cx, 0), NA - 1);
        int cy = vy + oy - R; cy = min(max(cy, 0), NB - 1);
        int cz = vz + oz - R; cz = min(max(cz, 0), NS - 1);

        float dx = qx - (float)cx;
        float dy = qy - (float)cy;
        float dz = qz - (float)cz;
        float d  = dx * dx + dy * dy + dz * dz;

        float m = rel[(cx * NB + cy) * NS + cz];
        float w = valid ? __expf(-d * inv_t) : 0.0f;
        sw  += w;
        swm += w * m;
    }
}

__device__ __noinline__ void soft_accum_generic(
    int tid, int vx, int vy, int vz, int K,
    float qx, float qy, float qz, float inv_t,
    const float* __restrict__ rel,
    float& sw, float& swm)
{
    const int K2 = K * K;
    const int K3 = K2 * K;
    const int R  = K / 2;
    for (int k = tid; k < K3; k += 256) {
        int ox  = k / K2;
        int rem = k - ox * K2;
        int oy  = rem / K;
        int oz  = rem - oy * K;
        int cx = vx + ox - R; cx = min(max(cx, 0), NA - 1);
        int cy = vy + oy - R; cy = min(max(cy, 0), NB - 1);
        int cz = vz + oz - R; cz = min(max(cz, 0), NS - 1);
        float dx = qx - (float)cx;
        float dy = qy - (float)cy;
        float dz = qz - (float)cz;
        float d  = dx * dx + dy * dy + dz * dz;
        float w = __expf(-d * inv_t);
        sw  += w;
        swm += w * rel[(cx * NB + cy) * NS + cz];
    }
}

__global__ __launch_bounds__(256) void latent_lookup_kernel(
    const float* __restrict__ q,        // [B,3]
    const float* __restrict__ rel,      // [NA*NB*NS]
    const float* __restrict__ origin,   // [3]
    const float* __restrict__ spacing,  // [3]
    const float* __restrict__ temp,     // [1]
    const int*   __restrict__ ksize,    // [1]
    float* __restrict__ out,            // [2,B]
    int B)
{
    const int b   = blockIdx.x;
    const int tid = threadIdx.x;

    const float qx = q[b * 3 + 0];
    const float qy = q[b * 3 + 1];
    const float qz = q[b * 3 + 2];

    // ---- hard path hoisted: issue the dependent gather FIRST so it is in
    // flight during the entire soft phase (load early, use late).
    float hardval = 0.0f;
    if (tid == 0) {
        // nearest lattice point; ties (frac==0.5) -> floor, matching argmin
        // first-minimum (lower flat index) semantics.
        float fx = floorf(qx); int hx = (int)fx + ((qx - fx) > 0.5f ? 1 : 0);
        float fy = floorf(qy); int hy = (int)fy + ((qy - fy) > 0.5f ? 1 : 0);
        float fz = floorf(qz); int hz = (int)fz + ((qz - fz) > 0.5f ? 1 : 0);
        hx = min(max(hx, 0), NA - 1);
        hy = min(max(hy, 0), NB - 1);
        hz = min(max(hz, 0), NS - 1);
        hardval = rel[(hx * NB + hy) * NS + hz];
    }

    const float inv_t = 1.0f / (temp[0] + 1e-8f);
    const int   ks    = ksize[0];

    // voxel = clip(rint((q - origin)/spacing), 1, N-2)
    const float rx = (qx - origin[0]) / spacing[0];
    const float ry = (qy - origin[1]) / spacing[1];
    const float rz = (qz - origin[2]) / spacing[2];
    int vx = (int)rintf(rx); vx = min(max(vx, 1), NA - 2);
    int vy = (int)rintf(ry); vy = min(max(vy, 1), NB - 2);
    int vz = (int)rintf(rz); vz = min(max(vz, 1), NS - 2);

    float sw  = 0.0f;
    float swm = 0.0f;

    if (ks == 15) {   // shipped configuration; uniform branch
        soft_accum_tpl<15>(tid, vx, vy, vz, qx, qy, qz, inv_t, rel, sw, swm);
    } else {
        soft_accum_generic(tid, vx, vy, vz, ks, qx, qy, qz, inv_t, rel, sw, swm);
    }

    // block reduction: wave64 shuffle, then LDS across waves
    __shared__ float red[4][2];
    const int wave = tid >> 6;
    const int lane = tid & 63;
    #pragma unroll
    for (int off = 32; off > 0; off >>= 1) {
        sw  += __shfl_down(sw,  off);
        swm += __shfl_down(swm, off);
    }
    if (lane == 0) {
        red[wave][0] = sw;
        red[wave][1] = swm;
    }
    __syncthreads();

    if (tid == 0) {
        float tsw = 0.0f, tswm = 0.0f;
        #pragma unroll
        for (int w = 0; w < 4; ++w) {
            tsw  += red[w][0];
            tswm += red[w][1];
        }
        out[b]     = hardval;        // hard (load issued at kernel top)
        out[B + b] = tswm / tsw;     // soft
    }
}

extern "C" void kernel_launch(void* const* d_in, const int* in_sizes, int n_in,
                              void* d_out, int out_size, void* d_ws, size_t ws_size,
                              hipStream_t stream) {
    const float* q       = (const float*)d_in[0];  // [B,3]
    // d_in[1] = indices_3d — unit meshgrid, synthesized arithmetically
    const float* rel     = (const float*)d_in[2];  // [NA,NB,NS]
    const float* origin  = (const float*)d_in[3];  // [3]
    const float* spacing = (const float*)d_in[4];  // [3]
    const float* temp    = (const float*)d_in[5];  // [1]
    const int*   ksize   = (const int*)d_in[6];    // [1]
    float* out = (float*)d_out;

    const int B = in_sizes[0] / 3;

    latent_lookup_kernel<<<B, 256, 0, stream>>>(q, rel, origin, spacing, temp,
                                                ksize, out, B);
}